// Round 4
// baseline (377.450 us; speedup 1.0000x reference)
//
#include <hip/hip_runtime.h>

typedef __attribute__((ext_vector_type(8))) short short8;
typedef __attribute__((ext_vector_type(8))) unsigned short us8;
typedef __attribute__((ext_vector_type(4))) unsigned short us4;
typedef __attribute__((ext_vector_type(4))) float f32x4;

static __device__ __forceinline__ unsigned short f2bf(float f) {
  union { float f; unsigned u; } c; c.f = f;
  unsigned r = (c.u + 0x7FFFu + ((c.u >> 16) & 1u)) >> 16;
  return (unsigned short)r;
}

static __device__ __forceinline__ void gll16(const unsigned short* g, unsigned short* l) {
  __builtin_amdgcn_global_load_lds(
      (const __attribute__((address_space(1))) unsigned int*)g,
      (__attribute__((address_space(3))) unsigned int*)l, 16, 0, 0);
}

// ---- weight/bias conversion
__global__ __launch_bounds__(256) void conv_k(
    const float* __restrict__ wq, const float* __restrict__ wk,
    const float* __restrict__ wv, const float* __restrict__ wp,
    const float* __restrict__ bq, const float* __restrict__ bk,
    unsigned short* __restrict__ wqk, unsigned short* __restrict__ wvb,
    unsigned short* __restrict__ wpb, float* __restrict__ bqk)
{
  int gid = blockIdx.x * 256 + threadIdx.x;
  int i4 = gid * 4;
  const float* src;
  unsigned short* dst;
  if (i4 < 524288) {
    src = (i4 < 262144) ? (wq + i4) : (wk + (i4 - 262144));
    dst = wqk + i4;
  } else if (i4 < 786432) {
    src = wv + (i4 - 524288);
    dst = wvb + (i4 - 524288);
  } else {
    src = wp + (i4 - 786432);
    dst = wpb + (i4 - 786432);
  }
  f32x4 v = *(const f32x4*)src;
  us4 o;
  #pragma unroll
  for (int j = 0; j < 4; ++j) o[j] = f2bf(v[j]);
  *(us4*)dst = o;
  if (gid < 1024)
    bqk[gid] = gid < 512 ? bq[gid] : bk[gid - 512];
}

// ---- GroupNorm -> hT [b][s=256][c=512] bf16
__global__ __launch_bounds__(512) void gn_k(
    const float* __restrict__ x, const float* __restrict__ gw,
    const float* __restrict__ gb, unsigned short* __restrict__ hT)
{
  __shared__ unsigned short tile[32][256];
  __shared__ float rs[2][4][2];
  const int b = blockIdx.x >> 4, gp = blockIdx.x & 15;
  const int tid = threadIdx.x;
  const int sub = tid >> 8;
  const int t = tid & 255;
  const int g = gp * 2 + sub;
  const float* xp = x + ((size_t)b * 512 + g * 16) * 256;
  f32x4 vals[4];
  float s = 0.f, s2 = 0.f;
  #pragma unroll
  for (int j = 0; j < 4; ++j) {
    f32x4 v = *(const f32x4*)(xp + j * 1024 + t * 4);
    vals[j] = v;
    s  += v[0] + v[1] + v[2] + v[3];
    s2 += v[0]*v[0] + v[1]*v[1] + v[2]*v[2] + v[3]*v[3];
  }
  #pragma unroll
  for (int o = 32; o; o >>= 1) { s += __shfl_xor(s, o); s2 += __shfl_xor(s2, o); }
  if ((t & 63) == 0) { rs[sub][t >> 6][0] = s; rs[sub][t >> 6][1] = s2; }
  __syncthreads();
  s  = rs[sub][0][0] + rs[sub][1][0] + rs[sub][2][0] + rs[sub][3][0];
  s2 = rs[sub][0][1] + rs[sub][1][1] + rs[sub][2][1] + rs[sub][3][1];
  const float mean = s * (1.f / 4096.f);
  const float var  = s2 * (1.f / 4096.f) - mean * mean;
  const float rstd = rsqrtf(var + 1e-5f);
  #pragma unroll
  for (int j = 0; j < 4; ++j) {
    const int cl = j * 4 + (t >> 6);
    const int c = g * 16 + cl;
    const float sc = gw[c] * rstd;
    const float sh = gb[c] - mean * sc;
    f32x4 v = vals[j];
    us4 o;
    #pragma unroll
    for (int q = 0; q < 4; ++q) o[q] = f2bf(v[q] * sc + sh);
    *(us4*)&tile[sub * 16 + cl][(t & 63) * 4] = o;
  }
  __syncthreads();
  const int srow = tid >> 1, half = tid & 1;
  us8 o0, o1;
  #pragma unroll
  for (int c = 0; c < 8; ++c) o0[c] = tile[half * 16 + c][srow];
  #pragma unroll
  for (int c = 0; c < 8; ++c) o1[c] = tile[half * 16 + 8 + c][srow];
  unsigned short* dst = hT + ((size_t)b * 256 + srow) * 512 + gp * 32 + half * 16;
  *(us8*)dst = o0;
  *(us8*)(dst + 8) = o1;
}

// ---- m201-style 256x256 GEMM, BK=64, 8 waves (2M x 4N), 4-phase/K-tile schedule,
// half-tile 4-slot LDS rings, counted vmcnt(6), setprio around MFMA clusters.
// C[bz][m][n] = sum_k A[m][k]*B[n][k]; A [M][K] (lda), B [N][K] (ldb), bf16.
template<int NT, int BIAS_MODE, bool OUT_F32, bool HAS_RESID, bool SOFTMAX>
__global__ __launch_bounds__(512, 2) void gemm3_k(
    const unsigned short* __restrict__ A, long long sAb, int lda,
    const unsigned short* __restrict__ B, long long sBb, int ldb,
    void* __restrict__ Cv, long long sCb, int ldc,
    const float* __restrict__ bias, const float* __restrict__ resid)
{
  static_assert(NT >= 2, "");
  __shared__ unsigned short As[4][8192];   // 4 half-tile slots x [128 rows][64 k]
  __shared__ unsigned short Bs[4][8192];
  const int tid = threadIdx.x;
  const int bz = blockIdx.z;
  const int bm = blockIdx.x * 256;
  const int bn = blockIdx.y * 256;
  const int lane = tid & 63, w = tid >> 6;
  const int wr = w >> 2, wc = w & 3;
  const int lr = lane & 15, lg = lane >> 4;
  const int csw = lr & 7;
  const int ko0 = (lg ^ csw) * 8;          // k-chunk byte/2 offsets (swizzled)
  const int ko1 = ((4 + lg) ^ csw) * 8;

  // staging geometry: thread covers chunks tid (row rl) and tid+512 (row rl+64)
  const int rl = tid >> 3;
  const int gc = (tid & 7) ^ (rl & 7);     // inverse-swizzled global chunk
  const unsigned short* pA = A + (size_t)bz * sAb + (size_t)(bm + rl) * lda + gc * 8;
  const unsigned short* pB = B + (size_t)bz * sBb + (size_t)(bn + rl) * ldb + gc * 8;

  auto stageA = [&](int t, int h) {
    const unsigned short* s = pA + (size_t)h * 128 * lda + t * 64;
    unsigned short* d = &As[(2 * t + h) & 3][tid * 8];
    gll16(s, d);
    gll16(s + (size_t)64 * lda, d + 4096);
  };
  auto stageB = [&](int t, int h) {
    const unsigned short* s = pB + (size_t)h * 128 * ldb + t * 64;
    unsigned short* d = &Bs[(2 * t + h) & 3][tid * 8];
    gll16(s, d);
    gll16(s + (size_t)64 * ldb, d + 4096);
  };

  f32x4 acc[8][4];
  #pragma unroll
  for (int i = 0; i < 8; ++i)
    #pragma unroll
    for (int j = 0; j < 4; ++j) acc[i][j] = (f32x4){0.f, 0.f, 0.f, 0.f};

  // prologue: tile0 all 4 halves, then tile1 {B0, A0, A1}; 3 halves stay in flight
  stageA(0, 0); stageA(0, 1); stageB(0, 0); stageB(0, 1);
  stageB(1, 0); stageA(1, 0); stageA(1, 1);
  asm volatile("s_waitcnt vmcnt(6)" ::: "memory");
  __builtin_amdgcn_s_barrier();

  for (int t = 0; t < NT; ++t) {
    const unsigned short* sA = &As[(2 * t + wr) & 3][0];
    const unsigned short* sB = &Bs[(2 * t + (wc >> 1)) & 3][0];
    const int bc = (wc & 1) * 64;
    short8 af[4][2], bf0[2][2], bf1[2][2];

    // ---- phase 1: read A rows 0-63(local) + B cols 0-31(local); stage B1(t+1)
    #pragma unroll
    for (int mi = 0; mi < 4; ++mi) {
      af[mi][0] = *(const short8*)(sA + (mi * 16 + lr) * 64 + ko0);
      af[mi][1] = *(const short8*)(sA + (mi * 16 + lr) * 64 + ko1);
    }
    #pragma unroll
    for (int nj = 0; nj < 2; ++nj) {
      bf0[nj][0] = *(const short8*)(sB + (bc + nj * 16 + lr) * 64 + ko0);
      bf0[nj][1] = *(const short8*)(sB + (bc + nj * 16 + lr) * 64 + ko1);
    }
    if (t + 1 < NT) stageB(t + 1, 1);
    __builtin_amdgcn_s_barrier();
    __builtin_amdgcn_s_setprio(1);
    #pragma unroll
    for (int mi = 0; mi < 4; ++mi)
      #pragma unroll
      for (int nj = 0; nj < 2; ++nj) {
        acc[mi][nj] = __builtin_amdgcn_mfma_f32_16x16x32_bf16(af[mi][0], bf0[nj][0], acc[mi][nj], 0, 0, 0);
        acc[mi][nj] = __builtin_amdgcn_mfma_f32_16x16x32_bf16(af[mi][1], bf0[nj][1], acc[mi][nj], 0, 0, 0);
      }
    __builtin_amdgcn_s_setprio(0);
    __builtin_amdgcn_s_barrier();

    // ---- phase 2: read B cols 32-63(local)
    #pragma unroll
    for (int nj = 0; nj < 2; ++nj) {
      bf1[nj][0] = *(const short8*)(sB + (bc + 32 + nj * 16 + lr) * 64 + ko0);
      bf1[nj][1] = *(const short8*)(sB + (bc + 32 + nj * 16 + lr) * 64 + ko1);
    }
    __builtin_amdgcn_s_barrier();
    __builtin_amdgcn_s_setprio(1);
    #pragma unroll
    for (int mi = 0; mi < 4; ++mi)
      #pragma unroll
      for (int nj = 0; nj < 2; ++nj) {
        acc[mi][2 + nj] = __builtin_amdgcn_mfma_f32_16x16x32_bf16(af[mi][0], bf1[nj][0], acc[mi][2 + nj], 0, 0, 0);
        acc[mi][2 + nj] = __builtin_amdgcn_mfma_f32_16x16x32_bf16(af[mi][1], bf1[nj][1], acc[mi][2 + nj], 0, 0, 0);
      }
    __builtin_amdgcn_s_setprio(0);
    __builtin_amdgcn_s_barrier();

    // ---- phase 3: read A rows 64-127(local); stage B0(t+2) (B slots freed after ph2)
    #pragma unroll
    for (int mi = 0; mi < 4; ++mi) {
      af[mi][0] = *(const short8*)(sA + (64 + mi * 16 + lr) * 64 + ko0);
      af[mi][1] = *(const short8*)(sA + (64 + mi * 16 + lr) * 64 + ko1);
    }
    if (t + 2 < NT) stageB(t + 2, 0);
    __builtin_amdgcn_s_barrier();
    __builtin_amdgcn_s_setprio(1);
    #pragma unroll
    for (int mi = 0; mi < 4; ++mi)
      #pragma unroll
      for (int nj = 0; nj < 2; ++nj) {
        acc[4 + mi][nj] = __builtin_amdgcn_mfma_f32_16x16x32_bf16(af[mi][0], bf0[nj][0], acc[4 + mi][nj], 0, 0, 0);
        acc[4 + mi][nj] = __builtin_amdgcn_mfma_f32_16x16x32_bf16(af[mi][1], bf0[nj][1], acc[4 + mi][nj], 0, 0, 0);
      }
    __builtin_amdgcn_s_setprio(0);
    __builtin_amdgcn_s_barrier();

    // ---- phase 4: stage A0,A1(t+2) (A slots freed after ph3); counted wait; close tile
    if (t + 2 < NT) { stageA(t + 2, 0); stageA(t + 2, 1); }
    __builtin_amdgcn_s_barrier();
    __builtin_amdgcn_s_setprio(1);
    #pragma unroll
    for (int mi = 0; mi < 4; ++mi)
      #pragma unroll
      for (int nj = 0; nj < 2; ++nj) {
        acc[4 + mi][2 + nj] = __builtin_amdgcn_mfma_f32_16x16x32_bf16(af[mi][0], bf1[nj][0], acc[4 + mi][2 + nj], 0, 0, 0);
        acc[4 + mi][2 + nj] = __builtin_amdgcn_mfma_f32_16x16x32_bf16(af[mi][1], bf1[nj][1], acc[4 + mi][2 + nj], 0, 0, 0);
      }
    __builtin_amdgcn_s_setprio(0);
    if (t == NT - 2)      asm volatile("s_waitcnt vmcnt(0)" ::: "memory");
    else if (t < NT - 2)  asm volatile("s_waitcnt vmcnt(6)" ::: "memory");
    __builtin_amdgcn_s_barrier();
  }

  if (SOFTMAX) {
    const float SC = 0.044194173824159216f;
    float* redm = (float*)&As[0][0];
    float* reds = redm + 1024;
    float rmax[8][4];
    #pragma unroll
    for (int mi = 0; mi < 8; ++mi)
      #pragma unroll
      for (int r = 0; r < 4; ++r) {
        float m = fmaxf(fmaxf(acc[mi][0][r], acc[mi][1][r]),
                        fmaxf(acc[mi][2][r], acc[mi][3][r]));
        #pragma unroll
        for (int o = 1; o <= 8; o <<= 1) m = fmaxf(m, __shfl_xor(m, o));
        rmax[mi][r] = m;
      }
    __syncthreads();
    if (lr == 0) {
      #pragma unroll
      for (int mi = 0; mi < 8; ++mi)
        #pragma unroll
        for (int r = 0; r < 4; ++r)
          redm[(wr * 128 + mi * 16 + lg * 4 + r) * 4 + wc] = rmax[mi][r];
    }
    __syncthreads();
    float rsum[8][4];
    #pragma unroll
    for (int mi = 0; mi < 8; ++mi)
      #pragma unroll
      for (int r = 0; r < 4; ++r) {
        const int row = wr * 128 + mi * 16 + lg * 4 + r;
        f32x4 q = *(const f32x4*)&redm[row * 4];
        const float m = fmaxf(fmaxf(q[0], q[1]), fmaxf(q[2], q[3]));
        float s = 0.f;
        #pragma unroll
        for (int ni = 0; ni < 4; ++ni) {
          float e = __expf((acc[mi][ni][r] - m) * SC);
          acc[mi][ni][r] = e;
          s += e;
        }
        #pragma unroll
        for (int o = 1; o <= 8; o <<= 1) s += __shfl_xor(s, o);
        rsum[mi][r] = s;
      }
    if (lr == 0) {
      #pragma unroll
      for (int mi = 0; mi < 8; ++mi)
        #pragma unroll
        for (int r = 0; r < 4; ++r)
          reds[(wr * 128 + mi * 16 + lg * 4 + r) * 4 + wc] = rsum[mi][r];
    }
    __syncthreads();
    unsigned short* Cb = (unsigned short*)Cv + (size_t)bz * sCb;
    #pragma unroll
    for (int mi = 0; mi < 8; ++mi)
      #pragma unroll
      for (int r = 0; r < 4; ++r) {
        const int row = wr * 128 + mi * 16 + lg * 4 + r;
        f32x4 q = *(const f32x4*)&reds[row * 4];
        const float inv = 1.f / (q[0] + q[1] + q[2] + q[3]);
        #pragma unroll
        for (int ni = 0; ni < 4; ++ni) {
          const int col = wc * 64 + ni * 16 + lr;
          Cb[(size_t)row * ldc + col] = f2bf(acc[mi][ni][r] * inv);
        }
      }
  } else {
    #pragma unroll
    for (int mi = 0; mi < 8; ++mi)
      #pragma unroll
      for (int r = 0; r < 4; ++r) {
        const int rowc = bm + wr * 128 + mi * 16 + lg * 4 + r;
        const float bv_ = (BIAS_MODE == 1) ? bias[rowc] : 0.f;
        #pragma unroll
        for (int ni = 0; ni < 4; ++ni) {
          const int col = bn + wc * 64 + ni * 16 + lr;
          float vv = acc[mi][ni][r] + bv_;
          if (BIAS_MODE == 2) vv += bias[col];
          const size_t idx = (size_t)bz * sCb + (size_t)rowc * ldc + col;
          if (HAS_RESID) vv += resid[idx];
          if (OUT_F32) ((float*)Cv)[idx] = vv;
          else ((unsigned short*)Cv)[idx] = f2bf(vv);
        }
      }
  }
}

extern "C" void kernel_launch(void* const* d_in, const int* in_sizes, int n_in,
                              void* d_out, int out_size, void* d_ws, size_t ws_size,
                              hipStream_t stream)
{
  const float* x   = (const float*)d_in[0];
  const float* gnw = (const float*)d_in[1];
  const float* gnb = (const float*)d_in[2];
  const float* wq  = (const float*)d_in[3];
  const float* bq  = (const float*)d_in[4];
  const float* wk  = (const float*)d_in[5];
  const float* bk  = (const float*)d_in[6];
  const float* wv  = (const float*)d_in[7];
  const float* bv  = (const float*)d_in[8];
  const float* wp  = (const float*)d_in[9];
  const float* bp  = (const float*)d_in[10];
  float* out = (float*)d_out;

  char* ws = (char*)d_ws;
  unsigned short* wqk  = (unsigned short*)(ws);                   // 1024x512 bf16
  unsigned short* wvb  = (unsigned short*)(ws + 1048576);         // 512x512 bf16
  unsigned short* wpb  = (unsigned short*)(ws + 1572864);         // 512x512 bf16
  float*          bqk  = (float*)(ws + 2097152);                  // 1024 f32
  unsigned short* hT   = (unsigned short*)(ws + 2101248);         // B*256*512 bf16 (reused as oT)
  unsigned short* qkT  = (unsigned short*)(ws + 69210112ull);     // B*256*1024 bf16
  unsigned short* v    = (unsigned short*)(ws + 203427840ull);    // B*512*256 bf16
  unsigned short* attb = (unsigned short*)(ws + 270536704ull);    // B*256*256 bf16
  unsigned short* oT   = hT;

  conv_k<<<1024, 256, 0, stream>>>(wq, wk, wv, wp, bq, bk, wqk, wvb, wpb, bqk);
  gn_k<<<4096, 512, 0, stream>>>(x, gnw, gnb, hT);
  // G1a: qkT (flat 65536 x 1024) = hT (flat 65536x512) x wqk^T ; bias per-col
  gemm3_k<8, 2, false, false, false><<<dim3(256, 4, 1), 512, 0, stream>>>(
      hT, 0, 512, wqk, 0, 512, qkT, 0, 1024, bqk, nullptr);
  // G1b: v[b][c][s] = wvb (512x512) x hT[b]^T ; bias per-row
  gemm3_k<8, 1, false, false, false><<<dim3(2, 1, 256), 512, 0, stream>>>(
      wvb, 0, 512, hT, 131072, 512, v, 131072, 256, bv, nullptr);
  // G2+softmax: attb[b][s][t] = softmax(q^T k / sqrt(512))
  gemm3_k<8, 0, false, false, true><<<dim3(1, 1, 256), 512, 0, stream>>>(
      qkT, 262144, 1024, qkT + 512, 262144, 1024, attb, 65536, 256, nullptr, nullptr);
  // G3: oT[b][t][c] = attb[b] (256x256) x v[b]^T
  gemm3_k<4, 0, false, false, false><<<dim3(1, 2, 256), 512, 0, stream>>>(
      attb, 65536, 256, v, 131072, 256, oT, 131072, 512, nullptr, nullptr);
  // G4: out[b][c][s] = wpb (512x512) x oT[b]^T + bp + x
  gemm3_k<8, 1, true, true, false><<<dim3(2, 1, 256), 512, 0, stream>>>(
      wpb, 0, 512, oT, 131072, 512, out, 131072, 256, bp, x);
}